// Round 1
// baseline (161.781 us; speedup 1.0000x reference)
//
#include <hip/hip_runtime.h>
#include <hip/hip_bf16.h>

#define BD 4
#define SD 2048
#define DD 512
#define VD 32000
#define NTOK (BD * SD)
#define EPS_L2 1e-12f

// Reduce two values across a 256-thread block (4 waves of 64).
__device__ inline void block_reduce2(float& a, float& b, float* sm) {
    #pragma unroll
    for (int off = 32; off; off >>= 1) {
        a += __shfl_xor(a, off, 64);
        b += __shfl_xor(b, off, 64);
    }
    int wid = threadIdx.x >> 6;
    int lane = threadIdx.x & 63;
    if (lane == 0) { sm[wid] = a; sm[4 + wid] = b; }
    __syncthreads();
    a = sm[0] + sm[1] + sm[2] + sm[3];
    b = sm[4] + sm[5] + sm[6] + sm[7];
    __syncthreads();
}

__device__ inline float block_reduce1(float a, float* sm) {
    #pragma unroll
    for (int off = 32; off; off >>= 1) a += __shfl_xor(a, off, 64);
    int wid = threadIdx.x >> 6;
    int lane = threadIdx.x & 63;
    if (lane == 0) sm[wid] = a;
    __syncthreads();
    float r = sm[0] + sm[1] + sm[2] + sm[3];
    __syncthreads();
    return r;
}

// One block per token. out[0] = loss accumulator, out[1..] = segment sums [V*D].
__global__ void __launch_bounds__(256)
token_kernel(const float* __restrict__ x, const float* __restrict__ p,
             const int* __restrict__ gold, const int* __restrict__ mask,
             const float* __restrict__ cache,
             float* __restrict__ out, float* __restrict__ counts) {
    __shared__ float sm[8];
    int t = blockIdx.x;
    int tid = threadIdx.x;
    int g = gold[t];
    int pad = mask[t];

    const float2* x2 = (const float2*)(x + (size_t)t * DD);
    const float2* c2 = (const float2*)(cache + (size_t)g * DD);
    float2 xv = x2[tid];
    float2 cv = c2[tid];

    float sx = xv.x * xv.x + xv.y * xv.y;
    float sc = cv.x * cv.x + cv.y * cv.y;
    block_reduce2(sx, sc, sm);

    float rnx = 1.0f / fmaxf(sqrtf(sx), EPS_L2);
    float rnc = 1.0f / fmaxf(sqrtf(sc), EPS_L2);

    float d0 = xv.x * rnx - cv.x * rnc;
    float d1 = xv.y * rnx - cv.y * rnc;
    float l = block_reduce1(d0 * d0 + d1 * d1, sm);

    if (tid == 0) {
        if (!pad) atomicAdd(out, l);
        atomicAdd(&counts[g], 1.0f);  // counts include padded tokens (ref semantics)
    }

    float pg = p[(size_t)t * VD + g];
    float w = pad ? 0.0f : pg;
    float* s = out + 1 + (size_t)g * DD + 2 * tid;
    atomicAdd(s, xv.x * w);
    atomicAdd(s + 1, xv.y * w);
}

// Elementwise finalize over V*D: out[1+idx] = counts[v]>0 ? 0.9*c + 0.1*sums/max(cnt,1) : c
__global__ void __launch_bounds__(256)
finalize_kernel(const float* __restrict__ cache, const float* __restrict__ counts,
                float* __restrict__ out) {
    size_t idx = (size_t)blockIdx.x * 256 + threadIdx.x;
    if (idx >= (size_t)VD * DD) return;
    int v = (int)(idx >> 9);  // / DD
    float cnt = counts[v];
    float c = cache[idx];
    float s = out[1 + idx];
    float r = c;
    if (cnt > 0.0f) {
        float avg = s / fmaxf(cnt, 1.0f);
        r = 0.9f * c + 0.1f * avg;
    }
    out[1 + idx] = r;
}

extern "C" void kernel_launch(void* const* d_in, const int* in_sizes, int n_in,
                              void* d_out, int out_size, void* d_ws, size_t ws_size,
                              hipStream_t stream) {
    const float* x = (const float*)d_in[0];
    const float* p = (const float*)d_in[1];
    const int* gold = (const int*)d_in[2];
    const int* mask = (const int*)d_in[3];
    const float* cache = (const float*)d_in[4];
    float* out = (float*)d_out;
    float* counts = (float*)d_ws;

    // Zero loss + segment-sum scratch (lives in d_out) and counts.
    hipMemsetAsync(out, 0, sizeof(float) * (size_t)(1 + (size_t)VD * DD), stream);
    hipMemsetAsync(counts, 0, sizeof(float) * VD, stream);

    token_kernel<<<NTOK, 256, 0, stream>>>(x, p, gold, mask, cache, out, counts);

    size_t n = (size_t)VD * DD;
    finalize_kernel<<<(int)((n + 255) / 256), 256, 0, stream>>>(cache, counts, out);
}

// Round 2
// 63.879 us; speedup vs baseline: 2.5326x; 2.5326x over previous
//
#include <hip/hip_runtime.h>
#include <hip/hip_bf16.h>

#define BD 4
#define SD 2048
#define DD 512
#define VD 32000
#define NTOK (BD * SD)
#define EPS_L2 1e-12f

__device__ inline float wave_sum(float v) {
    #pragma unroll
    for (int off = 32; off; off >>= 1) v += __shfl_xor(v, off, 64);
    return v;
}

// ws layout: [ sums V*D f32 ][ counts V f32 ][ lossTok NTOK f32 ]
#define WS_COUNTS ((size_t)VD * DD)
#define WS_LOSS (WS_COUNTS + VD)

// K1: one wave per token. Zero the gold row of sums (touched rows only),
// count tokens per vocab id. Duplicate zeroing of the same row is benign.
__global__ void __launch_bounds__(256)
zero_count_kernel(const int* __restrict__ gold, float* __restrict__ sums,
                  float* __restrict__ counts) {
    int t = blockIdx.x * 4 + (threadIdx.x >> 6);
    int lane = threadIdx.x & 63;
    int g = gold[t];
    float4* row = (float4*)(sums + (size_t)g * DD);
    float4 z = {0.f, 0.f, 0.f, 0.f};
    row[lane] = z;
    row[64 + lane] = z;
    if (lane == 0) atomicAdd(&counts[g], 1.0f);  // counts include padded tokens
}

// K2: one wave per token. Norms + loss via shuffle reduce (no LDS, no
// barriers). Rows with count==1 use plain float4 stores (no RMW).
__global__ void __launch_bounds__(256)
token_kernel(const float* __restrict__ x, const float* __restrict__ p,
             const int* __restrict__ gold, const int* __restrict__ mask,
             const float* __restrict__ cache, const float* __restrict__ counts,
             float* __restrict__ sums, float* __restrict__ lossTok) {
    int t = blockIdx.x * 4 + (threadIdx.x >> 6);
    int lane = threadIdx.x & 63;
    int g = gold[t];
    int pad = mask[t];

    const float4* xr = (const float4*)x + (size_t)t * (DD / 4);
    const float4* cr = (const float4*)cache + (size_t)g * (DD / 4);
    float4 xa = xr[lane], xb = xr[64 + lane];
    float4 ca = cr[lane], cb = cr[64 + lane];

    float sx = xa.x * xa.x + xa.y * xa.y + xa.z * xa.z + xa.w * xa.w
             + xb.x * xb.x + xb.y * xb.y + xb.z * xb.z + xb.w * xb.w;
    float sc = ca.x * ca.x + ca.y * ca.y + ca.z * ca.z + ca.w * ca.w
             + cb.x * cb.x + cb.y * cb.y + cb.z * cb.z + cb.w * cb.w;
    #pragma unroll
    for (int off = 32; off; off >>= 1) {
        sx += __shfl_xor(sx, off, 64);
        sc += __shfl_xor(sc, off, 64);
    }
    float rnx = 1.0f / fmaxf(sqrtf(sx), EPS_L2);
    float rnc = 1.0f / fmaxf(sqrtf(sc), EPS_L2);

    float d;
    float l = 0.f;
    d = xa.x * rnx - ca.x * rnc; l += d * d;
    d = xa.y * rnx - ca.y * rnc; l += d * d;
    d = xa.z * rnx - ca.z * rnc; l += d * d;
    d = xa.w * rnx - ca.w * rnc; l += d * d;
    d = xb.x * rnx - cb.x * rnc; l += d * d;
    d = xb.y * rnx - cb.y * rnc; l += d * d;
    d = xb.z * rnx - cb.z * rnc; l += d * d;
    d = xb.w * rnx - cb.w * rnc; l += d * d;
    l = wave_sum(l);
    if (lane == 0) lossTok[t] = pad ? 0.f : l;

    float w = pad ? 0.f : p[(size_t)t * VD + g];
    float* s = sums + (size_t)g * DD;
    bool excl = (counts[g] == 1.0f);  // wave-uniform
    if (excl) {
        float4 va = {xa.x * w, xa.y * w, xa.z * w, xa.w * w};
        float4 vb = {xb.x * w, xb.y * w, xb.z * w, xb.w * w};
        ((float4*)s)[lane] = va;
        ((float4*)s)[64 + lane] = vb;
    } else {
        int b = lane * 4;
        atomicAdd(s + b + 0, xa.x * w);
        atomicAdd(s + b + 1, xa.y * w);
        atomicAdd(s + b + 2, xa.z * w);
        atomicAdd(s + b + 3, xa.w * w);
        atomicAdd(s + 256 + b + 0, xb.x * w);
        atomicAdd(s + 256 + b + 1, xb.y * w);
        atomicAdd(s + 256 + b + 2, xb.z * w);
        atomicAdd(s + 256 + b + 3, xb.w * w);
    }
}

// K3: blend. float4 loads (aligned, in d_ws/cache), scalar dword stores to
// the misaligned out+1 region. Last block reduces the 8192 loss partials.
#define FIN_BLOCKS (VD * DD / (256 * 4))  // 16000
__global__ void __launch_bounds__(256)
finalize_kernel(const float* __restrict__ cache, const float* __restrict__ counts,
                const float* __restrict__ sums, const float* __restrict__ lossTok,
                float* __restrict__ out) {
    if (blockIdx.x == FIN_BLOCKS) {
        __shared__ float sm[4];
        float a = 0.f;
        for (int i = threadIdx.x; i < NTOK; i += 256) a += lossTok[i];
        a = wave_sum(a);
        if ((threadIdx.x & 63) == 0) sm[threadIdx.x >> 6] = a;
        __syncthreads();
        if (threadIdx.x == 0) out[0] = sm[0] + sm[1] + sm[2] + sm[3];
        return;
    }
    int i4 = blockIdx.x * 256 + threadIdx.x;  // float4 index into [V*D)
    int v = i4 >> 7;                          // 128 float4 per row
    float cnt = counts[v];
    float4 c = ((const float4*)cache)[i4];
    float4 r = c;
    if (cnt > 0.f) {
        float4 s = ((const float4*)sums)[i4];
        float k = 0.1f / cnt;
        r.x = 0.9f * c.x + s.x * k;
        r.y = 0.9f * c.y + s.y * k;
        r.z = 0.9f * c.z + s.z * k;
        r.w = 0.9f * c.w + s.w * k;
    }
    float* o = out + 1 + (size_t)i4 * 4;
    o[0] = r.x; o[1] = r.y; o[2] = r.z; o[3] = r.w;
}

extern "C" void kernel_launch(void* const* d_in, const int* in_sizes, int n_in,
                              void* d_out, int out_size, void* d_ws, size_t ws_size,
                              hipStream_t stream) {
    const float* x = (const float*)d_in[0];
    const float* p = (const float*)d_in[1];
    const int* gold = (const int*)d_in[2];
    const int* mask = (const int*)d_in[3];
    const float* cache = (const float*)d_in[4];
    float* out = (float*)d_out;
    float* ws = (float*)d_ws;
    float* sums = ws;
    float* counts = ws + WS_COUNTS;
    float* lossTok = ws + WS_LOSS;

    hipMemsetAsync(counts, 0, sizeof(float) * VD, stream);
    zero_count_kernel<<<NTOK / 4, 256, 0, stream>>>(gold, sums, counts);
    token_kernel<<<NTOK / 4, 256, 0, stream>>>(x, p, gold, mask, cache, counts,
                                               sums, lossTok);
    finalize_kernel<<<FIN_BLOCKS + 1, 256, 0, stream>>>(cache, counts, sums,
                                                        lossTok, out);
}

// Round 3
// 60.774 us; speedup vs baseline: 2.6620x; 1.0511x over previous
//
#include <hip/hip_runtime.h>
#include <hip/hip_bf16.h>

#define BD 4
#define SD 2048
#define DD 512
#define VD 32000
#define NTOK (BD * SD)
#define EPS_L2 1e-12f

// ws layout: [ counts V ][ lossTok NTOK ][ pgw NTOK ]
#define WS_LOSS VD
#define WS_PGW (VD + NTOK)

__device__ inline float wave_sum(float v) {
    #pragma unroll
    for (int off = 32; off; off >>= 1) v += __shfl_xor(v, off, 64);
    return v;
}

// K1: one wave per token. Counts, per-token loss, stash p[t,gold].
__global__ void __launch_bounds__(256)
token_stats_kernel(const float* __restrict__ x, const float* __restrict__ p,
                   const int* __restrict__ gold, const int* __restrict__ mask,
                   const float* __restrict__ cache, float* __restrict__ counts,
                   float* __restrict__ lossTok, float* __restrict__ pgw) {
    int t = blockIdx.x * 4 + (threadIdx.x >> 6);
    int lane = threadIdx.x & 63;
    int g = gold[t];
    int pad = mask[t];

    const float4* xr = (const float4*)x + (size_t)t * (DD / 4);
    const float4* cr = (const float4*)cache + (size_t)g * (DD / 4);
    float4 xa = xr[lane], xb = xr[64 + lane];
    float4 ca = cr[lane], cb = cr[64 + lane];

    float sx = xa.x * xa.x + xa.y * xa.y + xa.z * xa.z + xa.w * xa.w
             + xb.x * xb.x + xb.y * xb.y + xb.z * xb.z + xb.w * xb.w;
    float sc = ca.x * ca.x + ca.y * ca.y + ca.z * ca.z + ca.w * ca.w
             + cb.x * cb.x + cb.y * cb.y + cb.z * cb.z + cb.w * cb.w;
    #pragma unroll
    for (int off = 32; off; off >>= 1) {
        sx += __shfl_xor(sx, off, 64);
        sc += __shfl_xor(sc, off, 64);
    }
    float rnx = 1.0f / fmaxf(sqrtf(sx), EPS_L2);
    float rnc = 1.0f / fmaxf(sqrtf(sc), EPS_L2);

    float d, l = 0.f;
    d = xa.x * rnx - ca.x * rnc; l += d * d;
    d = xa.y * rnx - ca.y * rnc; l += d * d;
    d = xa.z * rnx - ca.z * rnc; l += d * d;
    d = xa.w * rnx - ca.w * rnc; l += d * d;
    d = xb.x * rnx - cb.x * rnc; l += d * d;
    d = xb.y * rnx - cb.y * rnc; l += d * d;
    d = xb.z * rnx - cb.z * rnc; l += d * d;
    d = xb.w * rnx - cb.w * rnc; l += d * d;
    l = wave_sum(l);

    if (lane == 0) {
        lossTok[t] = pad ? 0.f : l;
        pgw[t] = pad ? 0.f : p[(size_t)t * VD + g];
        atomicAdd(&counts[g], 1.0f);  // counts include padded tokens (ref)
    }
}

// K2: out[1+i] = (cnt>0 ? 0.9 : 1.0) * cache[i]; spare block reduces loss.
#define SEED_BLOCKS 8000  // V*D/4 float4 / (256 thr * 2)
__global__ void __launch_bounds__(256)
seed_kernel(const float* __restrict__ cache, const float* __restrict__ counts,
            const float* __restrict__ lossTok, float* __restrict__ out) {
    if (blockIdx.x == SEED_BLOCKS) {
        __shared__ float sm[4];
        float a = 0.f;
        for (int i = threadIdx.x; i < NTOK; i += 256) a += lossTok[i];
        a = wave_sum(a);
        if ((threadIdx.x & 63) == 0) sm[threadIdx.x >> 6] = a;
        __syncthreads();
        if (threadIdx.x == 0) out[0] = sm[0] + sm[1] + sm[2] + sm[3];
        return;
    }
    int i4 = blockIdx.x * 512 + threadIdx.x;
    #pragma unroll
    for (int r = 0; r < 2; ++r, i4 += 256) {
        int v = i4 >> 7;  // 128 float4 per vocab row
        float m = counts[v] > 0.f ? 0.9f : 1.0f;
        float4 c = ((const float4*)cache)[i4];
        float* o = out + 1 + (size_t)i4 * 4;
        o[0] = m * c.x; o[1] = m * c.y; o[2] = m * c.z; o[3] = m * c.w;
    }
}

// K3: one wave per token: out_row += (0.1*pg/cnt) * x. Plain RMW when this
// token is the row's only writer (cnt==1), atomics otherwise.
__global__ void __launch_bounds__(256)
scatter_kernel(const float* __restrict__ x, const int* __restrict__ gold,
               const float* __restrict__ counts, const float* __restrict__ pgw,
               float* __restrict__ out) {
    int t = blockIdx.x * 4 + (threadIdx.x >> 6);
    int lane = threadIdx.x & 63;
    float w = pgw[t];
    if (w == 0.f) return;  // padded (wave-uniform)
    int g = gold[t];
    float cnt = counts[g];
    float s = 0.1f * w / cnt;

    const float4* xr = (const float4*)x + (size_t)t * (DD / 4);
    float4 xa = xr[lane], xb = xr[64 + lane];
    float* o = out + 1 + (size_t)g * DD;
    int b = lane * 4;
    if (cnt == 1.0f) {
        o[b + 0] += s * xa.x; o[b + 1] += s * xa.y;
        o[b + 2] += s * xa.z; o[b + 3] += s * xa.w;
        o[256 + b + 0] += s * xb.x; o[256 + b + 1] += s * xb.y;
        o[256 + b + 2] += s * xb.z; o[256 + b + 3] += s * xb.w;
    } else {
        atomicAdd(o + b + 0, s * xa.x); atomicAdd(o + b + 1, s * xa.y);
        atomicAdd(o + b + 2, s * xa.z); atomicAdd(o + b + 3, s * xa.w);
        atomicAdd(o + 256 + b + 0, s * xb.x); atomicAdd(o + 256 + b + 1, s * xb.y);
        atomicAdd(o + 256 + b + 2, s * xb.z); atomicAdd(o + 256 + b + 3, s * xb.w);
    }
}

extern "C" void kernel_launch(void* const* d_in, const int* in_sizes, int n_in,
                              void* d_out, int out_size, void* d_ws, size_t ws_size,
                              hipStream_t stream) {
    const float* x = (const float*)d_in[0];
    const float* p = (const float*)d_in[1];
    const int* gold = (const int*)d_in[2];
    const int* mask = (const int*)d_in[3];
    const float* cache = (const float*)d_in[4];
    float* out = (float*)d_out;
    float* ws = (float*)d_ws;
    float* counts = ws;
    float* lossTok = ws + WS_LOSS;
    float* pgw = ws + WS_PGW;

    hipMemsetAsync(counts, 0, sizeof(float) * VD, stream);
    token_stats_kernel<<<NTOK / 4, 256, 0, stream>>>(x, p, gold, mask, cache,
                                                     counts, lossTok, pgw);
    seed_kernel<<<SEED_BLOCKS + 1, 256, 0, stream>>>(cache, counts, lossTok, out);
    scatter_kernel<<<NTOK / 4, 256, 0, stream>>>(x, gold, counts, pgw, out);
}

// Round 4
// 39.096 us; speedup vs baseline: 4.1380x; 1.5545x over previous
//
#include <hip/hip_runtime.h>
#include <hip/hip_bf16.h>

#define BD 4
#define SD 2048
#define DD 512
#define VD 32000
#define NTOK (BD * SD)
#define EPS_L2 1e-12f

// ws layout: [ head V int ][ next NTOK int ][ lossPart 256 f32 ]
#define WS_NEXT VD
#define WS_LOSSP (VD + NTOK)

// K1: token -> per-vocab-row linked list. Block 0 also zeroes loss partials.
__global__ void __launch_bounds__(256)
build_kernel(const int* __restrict__ gold, int* __restrict__ head,
             int* __restrict__ next, float* __restrict__ lossPart) {
    int t = blockIdx.x * 256 + threadIdx.x;
    if (blockIdx.x == 0) lossPart[threadIdx.x] = 0.f;
    int g = gold[t];
    next[t] = atomicExch(&head[g], t);
}

// K2: one wave per vocab row. Walk token list: count, loss (2-2cos), and
// blended output in a single pass over cache/out.
__global__ void __launch_bounds__(256)
row_kernel(const float* __restrict__ x, const float* __restrict__ p,
           const int* __restrict__ mask, const float* __restrict__ cache,
           const int* __restrict__ head, const int* __restrict__ next,
           float* __restrict__ out, float* __restrict__ lossPart) {
    int row = blockIdx.x * 4 + (threadIdx.x >> 6);
    int lane = threadIdx.x & 63;
    const float4* cr = (const float4*)cache + (size_t)row * (DD / 4);
    float4 ca = cr[lane], cb = cr[64 + lane];
    float* o = out + 1 + (size_t)row * DD;
    int b = lane * 4;

    int t = head[row];
    if (t < 0) {  // untouched row: passthrough
        o[b + 0] = ca.x; o[b + 1] = ca.y; o[b + 2] = ca.z; o[b + 3] = ca.w;
        o[256 + b + 0] = cb.x; o[256 + b + 1] = cb.y;
        o[256 + b + 2] = cb.z; o[256 + b + 3] = cb.w;
        return;
    }

    float sc = ca.x * ca.x + ca.y * ca.y + ca.z * ca.z + ca.w * ca.w
             + cb.x * cb.x + cb.y * cb.y + cb.z * cb.z + cb.w * cb.w;
    #pragma unroll
    for (int off = 32; off; off >>= 1) sc += __shfl_xor(sc, off, 64);
    float rnc = 1.0f / fmaxf(sqrtf(sc), EPS_L2);

    float4 aa = {0.f, 0.f, 0.f, 0.f}, ab = {0.f, 0.f, 0.f, 0.f};
    float lossAcc = 0.f;
    int cnt = 0;
    while (t >= 0) {
        int tn = next[t];  // prefetch the walk pointer
        int pad = mask[t];
        float pg = p[(size_t)t * VD + row];  // broadcast load
        const float4* xr = (const float4*)x + (size_t)t * (DD / 4);
        float4 xa = xr[lane], xb = xr[64 + lane];

        float dot = xa.x * ca.x + xa.y * ca.y + xa.z * ca.z + xa.w * ca.w
                  + xb.x * cb.x + xb.y * cb.y + xb.z * cb.z + xb.w * cb.w;
        float sx = xa.x * xa.x + xa.y * xa.y + xa.z * xa.z + xa.w * xa.w
                 + xb.x * xb.x + xb.y * xb.y + xb.z * xb.z + xb.w * xb.w;
        #pragma unroll
        for (int off = 32; off; off >>= 1) {
            dot += __shfl_xor(dot, off, 64);
            sx += __shfl_xor(sx, off, 64);
        }
        cnt++;  // counts include padded tokens (ref semantics)
        if (!pad) {
            float rnx = 1.0f / fmaxf(sqrtf(sx), EPS_L2);
            lossAcc += 2.f - 2.f * dot * rnx * rnc;
            aa.x += pg * xa.x; aa.y += pg * xa.y;
            aa.z += pg * xa.z; aa.w += pg * xa.w;
            ab.x += pg * xb.x; ab.y += pg * xb.y;
            ab.z += pg * xb.z; ab.w += pg * xb.w;
        }
        t = tn;
    }

    float m = 0.1f / (float)cnt;
    o[b + 0] = 0.9f * ca.x + m * aa.x;
    o[b + 1] = 0.9f * ca.y + m * aa.y;
    o[b + 2] = 0.9f * ca.z + m * aa.z;
    o[b + 3] = 0.9f * ca.w + m * aa.w;
    o[256 + b + 0] = 0.9f * cb.x + m * ab.x;
    o[256 + b + 1] = 0.9f * cb.y + m * ab.y;
    o[256 + b + 2] = 0.9f * cb.z + m * ab.z;
    o[256 + b + 3] = 0.9f * cb.w + m * ab.w;

    if (lane == 0) atomicAdd(&lossPart[row & 255], lossAcc);
}

// K3: reduce 256 loss partials -> out[0].
__global__ void __launch_bounds__(256)
loss_reduce_kernel(const float* __restrict__ lossPart, float* __restrict__ out) {
    __shared__ float sm[4];
    float a = lossPart[threadIdx.x];
    #pragma unroll
    for (int off = 32; off; off >>= 1) a += __shfl_xor(a, off, 64);
    if ((threadIdx.x & 63) == 0) sm[threadIdx.x >> 6] = a;
    __syncthreads();
    if (threadIdx.x == 0) out[0] = sm[0] + sm[1] + sm[2] + sm[3];
}

extern "C" void kernel_launch(void* const* d_in, const int* in_sizes, int n_in,
                              void* d_out, int out_size, void* d_ws, size_t ws_size,
                              hipStream_t stream) {
    const float* x = (const float*)d_in[0];
    const float* p = (const float*)d_in[1];
    const int* gold = (const int*)d_in[2];
    const int* mask = (const int*)d_in[3];
    const float* cache = (const float*)d_in[4];
    float* out = (float*)d_out;
    int* head = (int*)d_ws;
    int* next = head + WS_NEXT;
    float* lossPart = (float*)d_ws + WS_LOSSP;

    hipMemsetAsync(head, 0xFF, sizeof(int) * VD, stream);  // head = -1
    build_kernel<<<NTOK / 256, 256, 0, stream>>>(gold, head, next, lossPart);
    row_kernel<<<VD / 4, 256, 0, stream>>>(x, p, mask, cache, head, next, out,
                                           lossPart);
    loss_reduce_kernel<<<1, 256, 0, stream>>>(lossPart, out);
}